// Round 14
// baseline (153.827 us; speedup 1.0000x reference)
//
#include <hip/hip_runtime.h>
#include <hip/hip_bf16.h>
#include <stdint.h>

#define N_ROWS 8192
#define DIM    768          // elements per row; == BYTES per row in int8
#define BM     256
#define BN     256
#define BKB    128          // K-tile bytes (= i8 elements)
#define KTILES (DIM / BKB)  // 6
#define NT2    (N_ROWS / BN)
#define LDS_BYTES 65536

typedef __attribute__((ext_vector_type(4)))  int   i32x4;
typedef __attribute__((ext_vector_type(4)))  float f32x4;

__device__ __forceinline__ float tstudent(float c) {
    // (1 + 0.5*(1-c))^{-1.5} = t^{-1.5}, t = 1.5 - 0.5c
    float t = 1.5f - 0.5f * c;
    float r = rsqrtf(t);
    return r * r * r;
}

// ---------------- kernel 1: row L2-normalize fp32 -> int8, fp32 diag numerator, post-quant inv-norms ----------------
__global__ __launch_bounds__(256) void norm_kernel(const float* __restrict__ z1,
                                                   const float* __restrict__ z2,
                                                   signed char* __restrict__ n1,
                                                   signed char* __restrict__ n2,
                                                   float* __restrict__ num,
                                                   float* __restrict__ inva,
                                                   float* __restrict__ invb) {
    int row = blockIdx.x;
    int t = threadIdx.x;
    const float* s1 = z1 + (size_t)row * DIM;
    const float* s2 = z2 + (size_t)row * DIM;
    float a0 = s1[t], a1 = s1[t + 256], a2 = s1[t + 512];
    float b0 = s2[t], b1 = s2[t + 256], b2 = s2[t + 512];
    float ss1 = a0 * a0 + a1 * a1 + a2 * a2;
    float ss2 = b0 * b0 + b1 * b1 + b2 * b2;
    float sd  = a0 * b0 + a1 * b1 + a2 * b2;
    for (int off = 32; off; off >>= 1) {
        ss1 += __shfl_down(ss1, off);
        ss2 += __shfl_down(ss2, off);
        sd  += __shfl_down(sd, off);
    }
    __shared__ float w1[4], w2[4], wd[4];
    __shared__ float sc1_s, sc2_s;
    if ((t & 63) == 0) { int wi = t >> 6; w1[wi] = ss1; w2[wi] = ss2; wd[wi] = sd; }
    __syncthreads();
    if (t == 0) {
        float nrm1 = fmaxf(sqrtf(w1[0] + w1[1] + w1[2] + w1[3]), 1e-8f);
        float nrm2 = fmaxf(sqrtf(w2[0] + w2[1] + w2[2] + w2[3]), 1e-8f);
        float dot  = wd[0] + wd[1] + wd[2] + wd[3];
        sc1_s = 127.0f / nrm1;
        sc2_s = 127.0f / nrm2;
        num[row] = tstudent(dot / (nrm1 * nrm2));   // numerator exact in fp32
    }
    __syncthreads();
    float sc1 = sc1_s, sc2 = sc2_s;
    float qa0 = fminf(fmaxf(rintf(a0 * sc1), -127.f), 127.f);
    float qa1 = fminf(fmaxf(rintf(a1 * sc1), -127.f), 127.f);
    float qa2 = fminf(fmaxf(rintf(a2 * sc1), -127.f), 127.f);
    float qb0 = fminf(fmaxf(rintf(b0 * sc2), -127.f), 127.f);
    float qb1 = fminf(fmaxf(rintf(b1 * sc2), -127.f), 127.f);
    float qb2 = fminf(fmaxf(rintf(b2 * sc2), -127.f), 127.f);
    signed char* d1 = n1 + (size_t)row * DIM;
    signed char* d2 = n2 + (size_t)row * DIM;
    d1[t]       = (signed char)(int)qa0;
    d1[t + 256] = (signed char)(int)qa1;
    d1[t + 512] = (signed char)(int)qa2;
    d2[t]       = (signed char)(int)qb0;
    d2[t + 256] = (signed char)(int)qb1;
    d2[t + 512] = (signed char)(int)qb2;
    float sq1 = qa0 * qa0 + qa1 * qa1 + qa2 * qa2;
    float sq2 = qb0 * qb0 + qb1 * qb1 + qb2 * qb2;
    for (int off = 32; off; off >>= 1) {
        sq1 += __shfl_down(sq1, off);
        sq2 += __shfl_down(sq2, off);
    }
    __shared__ float wq1[4], wq2[4];
    if ((t & 63) == 0) { int wi = t >> 6; wq1[wi] = sq1; wq2[wi] = sq2; }
    __syncthreads();
    if (t == 0) {
        inva[row] = rsqrtf(wq1[0] + wq1[1] + wq1[2] + wq1[3]);
        invb[row] = rsqrtf(wq2[0] + wq2[1] + wq2[2] + wq2[3]);
    }
}

// ---------------- kernel 2: 256x256 16-wave int8 MFMA GEMM, TLP + split-ks + WAVE STAGGER ----------------
// R12 structure verbatim (1024 threads = 16 waves 4x4, per-wave 64x64 out, acc in AGPRs,
// A and B both staged through LDS with slot = granule ^ (row&7) swizzle, linear LDS dest +
// inverse-swizzled global source, 2-phase split-ks tile, single VMW(0)+BAR per tile).
// R14 change: ODD waves execute HALFK(seg1) before HALFK(seg0) (even waves seg0-first).
// Integer adds are order-invariant -> bit-identical. Effect: after each barrier, half the
// waves are in their LDS-read window while the other half are in their MFMA window —
// de-synchronizes the block-wide LDS storm / MFMA burst alternation that left both pipes
// <50% busy in R12 (LDS ~3072 cyc + MFMA ~2611 cyc vs 7150 measured, near-zero overlap).

__device__ __forceinline__ void stG(const signed char* g, char* lds, int t, int j) {
    __builtin_amdgcn_global_load_lds(
        (const __attribute__((address_space(1))) void*)(g + (size_t)j * 128 * DIM),
        (__attribute__((address_space(3))) void*)(lds + t * 16 + j * 16384), 16, 0, 0);
}

#define BAR()  asm volatile("s_barrier" ::: "memory")
#define VMW(n) asm volatile("s_waitcnt vmcnt(" #n ")" ::: "memory")

// One k-half (64 k-bytes): 4 B-frags at SEG, then per-m JIT A-read + 4 MFMAs.
#define HALFK(SEG)                                                              \
    {                                                                           \
        i32x4 b0 = *(const i32x4*)(Bb + rbB + 0 * 2048 + (SEG));                \
        i32x4 b1 = *(const i32x4*)(Bb + rbB + 1 * 2048 + (SEG));                \
        i32x4 b2 = *(const i32x4*)(Bb + rbB + 2 * 2048 + (SEG));                \
        i32x4 b3 = *(const i32x4*)(Bb + rbB + 3 * 2048 + (SEG));                \
        _Pragma("unroll")                                                       \
        for (int m = 0; m < 4; ++m) {                                           \
            i32x4 a = *(const i32x4*)(Ab + rbA + m * 2048 + (SEG));             \
            __builtin_amdgcn_s_setprio(1);                                      \
            acc[m][0] = __builtin_amdgcn_mfma_i32_16x16x64_i8(a, b0, acc[m][0], 0, 0, 0); \
            acc[m][1] = __builtin_amdgcn_mfma_i32_16x16x64_i8(a, b1, acc[m][1], 0, 0, 0); \
            acc[m][2] = __builtin_amdgcn_mfma_i32_16x16x64_i8(a, b2, acc[m][2], 0, 0, 0); \
            acc[m][3] = __builtin_amdgcn_mfma_i32_16x16x64_i8(a, b3, acc[m][3], 0, 0, 0); \
            __builtin_amdgcn_s_setprio(0);                                      \
        }                                                                       \
    }

__global__ __launch_bounds__(1024) void gemm_kernel(const signed char* __restrict__ n1,
                                                    const signed char* __restrict__ n2,
                                                    const float* __restrict__ inva,
                                                    const float* __restrict__ invb,
                                                    float* __restrict__ partial) {
    extern __shared__ char smem[];
    int t = threadIdx.x;
    int l = t & 63;
    int w = t >> 6;    // 0..15
    int wr = w >> 2;   // 0..3 -> A 64-row band
    int wc = w & 3;    // 0..3 -> B 64-col band
    int stag = w & 1;  // wave stagger parity

    // XCD-aware + L2 supertile mapping (1024 blocks, bijective)
    int bid = blockIdx.x;
    int xcd = bid & 7, idx = bid >> 3;
    int br = xcd * 4 + (idx & 3);
    int bc = (idx >> 4) * 4 + ((idx >> 2) & 3);
    int rowbase = br * BM, colbase = bc * BN;

    // staging: thread t covers LDS row sr = t>>3 (+128j), granule t&7;
    // inverse-swizzled global 16B-granule = (t&7) ^ (sr&7)
    int sr = t >> 3;
    int gcol0 = ((t & 7) ^ (sr & 7)) * 16;
    const signed char* Ag = n1 + (size_t)(rowbase + sr) * DIM + gcol0;
    const signed char* Bg = n2 + (size_t)(colbase + sr) * DIM + gcol0;

    i32x4 acc[4][4] = {};   // 64 regs (AGPR)

    // read side: frag row r = l&15 (bands multiples of 64 -> r&7 = l&7),
    // true granule = (l>>4) + 4*ks, slot = granule ^ (l&7)
    int seg0 = (((l >> 4) + 0) ^ (l & 7)) * 16;
    int seg1 = (((l >> 4) + 4) ^ (l & 7)) * 16;
    int rbA = (wr * 64 + (l & 15)) * 128;
    int rbB = (wc * 64 + (l & 15)) * 128;

    // prologue: stage K-tile 0 into parity 0
    stG(Ag, smem, t, 0);         stG(Ag, smem, t, 1);
    stG(Bg, smem + 65536, t, 0); stG(Bg, smem + 65536, t, 1);
    VMW(0); BAR();

    #pragma unroll
    for (int kt = 0; kt < KTILES - 1; ++kt) {
        int db = kt & 1;
        const char* Ab = smem + db * 32768;
        const char* Bb = smem + 65536 + db * 32768;
        char* AnW = smem + (db ^ 1) * 32768;
        char* BnW = smem + 65536 + (db ^ 1) * 32768;
        const signed char* Agn = Ag + (kt + 1) * BKB;
        const signed char* Bgn = Bg + (kt + 1) * BKB;

        // stage next tile, then compute both k-halves (stagger: odd waves seg1-first)
        stG(Agn, AnW, t, 0); stG(Agn, AnW, t, 1);
        stG(Bgn, BnW, t, 0); stG(Bgn, BnW, t, 1);
        if (stag) {
            HALFK(seg1);
            HALFK(seg0);
        } else {
            HALFK(seg0);
            HALFK(seg1);
        }
        VMW(0); BAR();
    }
    {   // peeled last tile (kt = 5, parity 1): no staging
        const char* Ab = smem + 32768;
        const char* Bb = smem + 65536 + 32768;
        if (stag) {
            HALFK(seg1);
            HALFK(seg0);
        } else {
            HALFK(seg0);
            HALFK(seg1);
        }
    }

    // ---------------- epilogue: cos = acc * inva[row] * invb[col]; t-Student + row sums ----------------
    // C/D map: row = wr*64 + m*16 + (l>>4)*4 + j (A-side), col = wc*64 + n*16 + (l&15)
    float invb_n[4];
    #pragma unroll
    for (int n = 0; n < 4; ++n)
        invb_n[n] = invb[colbase + wc * 64 + n * 16 + (l & 15)];

    float* red = (float*)smem;  // 256 rows x 4 wc
    __syncthreads();
    #pragma unroll
    for (int m = 0; m < 4; ++m) {
        f32x4 ia = *(const f32x4*)(inva + rowbase + wr * 64 + m * 16 + (l >> 4) * 4);
        #pragma unroll
        for (int j = 0; j < 4; ++j) {
            float s = 0.f;
            #pragma unroll
            for (int n = 0; n < 4; ++n) {
                float cos = (float)acc[m][n][j] * ia[j] * invb_n[n];
                s += tstudent(cos);
            }
            s += __shfl_xor(s, 1);
            s += __shfl_xor(s, 2);
            s += __shfl_xor(s, 4);
            s += __shfl_xor(s, 8);
            if ((l & 15) == 0) {
                int row = wr * 64 + m * 16 + (l >> 4) * 4 + j;
                red[row * 4 + wc] = s;
            }
        }
    }
    __syncthreads();
    if (t < BM) {
        partial[(size_t)bc * N_ROWS + rowbase + t] = red[t * 4 + 0] + red[t * 4 + 1] + red[t * 4 + 2] + red[t * 4 + 3];
    }
}

// ---------------- kernel 3: per-row denom + ratio, per-block sums ----------------
__global__ __launch_bounds__(256) void reduce_kernel(const float* __restrict__ partial,
                                                     const float* __restrict__ num,
                                                     float* __restrict__ blocksum) {
    int row = blockIdx.x * 256 + threadIdx.x;
    float d = 0.f;
    #pragma unroll 8
    for (int ct = 0; ct < NT2; ++ct) d += partial[(size_t)ct * N_ROWS + row];
    float s = num[row] / d;
    for (int off = 32; off; off >>= 1) s += __shfl_down(s, off);
    __shared__ float wsum[4];
    if ((threadIdx.x & 63) == 0) wsum[threadIdx.x >> 6] = s;
    __syncthreads();
    if (threadIdx.x == 0) blocksum[blockIdx.x] = wsum[0] + wsum[1] + wsum[2] + wsum[3];
}

// ---------------- kernel 4: final scalar ----------------
__global__ __launch_bounds__(64) void final_kernel(const float* __restrict__ blocksum,
                                                   float* __restrict__ out) {
    int l = threadIdx.x;
    float s = (l < 32) ? blocksum[l] : 0.f;
    for (int off = 32; off; off >>= 1) s += __shfl_down(s, off);
    if (l == 0) out[0] = -(s / (float)N_ROWS);
}

extern "C" void kernel_launch(void* const* d_in, const int* in_sizes, int n_in,
                              void* d_out, int out_size, void* d_ws, size_t ws_size,
                              hipStream_t stream) {
    const float* z1 = (const float*)d_in[0];
    const float* z2 = (const float*)d_in[1];
    char* ws = (char*)d_ws;
    const size_t n_bytes = (size_t)N_ROWS * DIM;   // 6,291,456 (int8)
    signed char* n1 = (signed char*)ws;
    signed char* n2 = (signed char*)(ws + n_bytes);
    size_t base2 = 2 * n_bytes;
    float* num      = (float*)(ws + base2);                    // 32 KB
    float* inva     = (float*)(ws + base2 + 32768);            // 32 KB
    float* invb     = (float*)(ws + base2 + 65536);            // 32 KB
    float* partial  = (float*)(ws + base2 + 98304);            // 1 MB used
    float* blocksum = (float*)(ws + base2 + 98304 + 2097152);  // 128 B

    hipFuncSetAttribute((const void*)gemm_kernel,
                        hipFuncAttributeMaxDynamicSharedMemorySize, LDS_BYTES);

    norm_kernel<<<N_ROWS, 256, 0, stream>>>(z1, z2, n1, n2, num, inva, invb);
    gemm_kernel<<<NT2 * NT2, 1024, LDS_BYTES, stream>>>(n1, n2, inva, invb, partial);
    reduce_kernel<<<N_ROWS / 256, 256, 0, stream>>>(partial, num, blocksum);
    final_kernel<<<1, 64, 0, stream>>>(blocksum, (float*)d_out);
}

// Round 15
// 83.533 us; speedup vs baseline: 1.8415x; 1.8415x over previous
//
#include <hip/hip_runtime.h>
#include <hip/hip_bf16.h>
#include <stdint.h>

#define N_ROWS 8192
#define DIM    768          // elements per row; == BYTES per row in int8
#define BM     256
#define BN     256
#define BKB    128          // K-tile bytes (= i8 elements)
#define KTILES (DIM / BKB)  // 6
#define NT2    (N_ROWS / BN)
#define LDS_BYTES 65536

typedef __attribute__((ext_vector_type(4)))  int   i32x4;
typedef __attribute__((ext_vector_type(4)))  float f32x4;

__device__ __forceinline__ float tstudent(float c) {
    // (1 + 0.5*(1-c))^{-1.5} = t^{-1.5}, t = 1.5 - 0.5c
    float t = 1.5f - 0.5f * c;
    float r = rsqrtf(t);
    return r * r * r;
}

// ---------------- kernel 1: row L2-normalize fp32 -> int8, fp32 diag numerator, post-quant inv-norms ----------------
__global__ __launch_bounds__(256) void norm_kernel(const float* __restrict__ z1,
                                                   const float* __restrict__ z2,
                                                   signed char* __restrict__ n1,
                                                   signed char* __restrict__ n2,
                                                   float* __restrict__ num,
                                                   float* __restrict__ inva,
                                                   float* __restrict__ invb) {
    int row = blockIdx.x;
    int t = threadIdx.x;
    const float* s1 = z1 + (size_t)row * DIM;
    const float* s2 = z2 + (size_t)row * DIM;
    float a0 = s1[t], a1 = s1[t + 256], a2 = s1[t + 512];
    float b0 = s2[t], b1 = s2[t + 256], b2 = s2[t + 512];
    float ss1 = a0 * a0 + a1 * a1 + a2 * a2;
    float ss2 = b0 * b0 + b1 * b1 + b2 * b2;
    float sd  = a0 * b0 + a1 * b1 + a2 * b2;
    for (int off = 32; off; off >>= 1) {
        ss1 += __shfl_down(ss1, off);
        ss2 += __shfl_down(ss2, off);
        sd  += __shfl_down(sd, off);
    }
    __shared__ float w1[4], w2[4], wd[4];
    __shared__ float sc1_s, sc2_s;
    if ((t & 63) == 0) { int wi = t >> 6; w1[wi] = ss1; w2[wi] = ss2; wd[wi] = sd; }
    __syncthreads();
    if (t == 0) {
        float nrm1 = fmaxf(sqrtf(w1[0] + w1[1] + w1[2] + w1[3]), 1e-8f);
        float nrm2 = fmaxf(sqrtf(w2[0] + w2[1] + w2[2] + w2[3]), 1e-8f);
        float dot  = wd[0] + wd[1] + wd[2] + wd[3];
        sc1_s = 127.0f / nrm1;
        sc2_s = 127.0f / nrm2;
        num[row] = tstudent(dot / (nrm1 * nrm2));   // numerator exact in fp32
    }
    __syncthreads();
    float sc1 = sc1_s, sc2 = sc2_s;
    float qa0 = fminf(fmaxf(rintf(a0 * sc1), -127.f), 127.f);
    float qa1 = fminf(fmaxf(rintf(a1 * sc1), -127.f), 127.f);
    float qa2 = fminf(fmaxf(rintf(a2 * sc1), -127.f), 127.f);
    float qb0 = fminf(fmaxf(rintf(b0 * sc2), -127.f), 127.f);
    float qb1 = fminf(fmaxf(rintf(b1 * sc2), -127.f), 127.f);
    float qb2 = fminf(fmaxf(rintf(b2 * sc2), -127.f), 127.f);
    signed char* d1 = n1 + (size_t)row * DIM;
    signed char* d2 = n2 + (size_t)row * DIM;
    d1[t]       = (signed char)(int)qa0;
    d1[t + 256] = (signed char)(int)qa1;
    d1[t + 512] = (signed char)(int)qa2;
    d2[t]       = (signed char)(int)qb0;
    d2[t + 256] = (signed char)(int)qb1;
    d2[t + 512] = (signed char)(int)qb2;
    float sq1 = qa0 * qa0 + qa1 * qa1 + qa2 * qa2;
    float sq2 = qb0 * qb0 + qb1 * qb1 + qb2 * qb2;
    for (int off = 32; off; off >>= 1) {
        sq1 += __shfl_down(sq1, off);
        sq2 += __shfl_down(sq2, off);
    }
    __shared__ float wq1[4], wq2[4];
    if ((t & 63) == 0) { int wi = t >> 6; wq1[wi] = sq1; wq2[wi] = sq2; }
    __syncthreads();
    if (t == 0) {
        inva[row] = rsqrtf(wq1[0] + wq1[1] + wq1[2] + wq1[3]);
        invb[row] = rsqrtf(wq2[0] + wq2[1] + wq2[2] + wq2[3]);
    }
}

// ---------------- kernel 2: 256x256 16-wave int8 MFMA GEMM, TLP + split-ks + cselect wave-stagger ----------------
// R12 structure verbatim (1024 threads = 16 waves 4x4, per-wave 64x64 out, acc in AGPRs,
// A and B staged through LDS, slot = granule ^ (row&7) swizzle, linear LDS dest +
// inverse-swizzled global source, 2-phase split-ks tile, single VMW(0)+BAR per tile).
// R15 change: per-wave k-half ORDER selected by runtime ternary (odd waves seg1-first) —
// single code path (R14's if/else duplication re-triggered the spill; this adds only two
// v_cndmask). Integer accumulation is order-invariant -> bit-identical. Intent: after
// each barrier, half the waves are in their LDS-read window while the other half are in
// their MFMA window, overlapping the two pipes that R12 left at 43%/36% busy.

__device__ __forceinline__ void stG(const signed char* g, char* lds, int t, int j) {
    __builtin_amdgcn_global_load_lds(
        (const __attribute__((address_space(1))) void*)(g + (size_t)j * 128 * DIM),
        (__attribute__((address_space(3))) void*)(lds + t * 16 + j * 16384), 16, 0, 0);
}

#define BAR()  asm volatile("s_barrier" ::: "memory")
#define VMW(n) asm volatile("s_waitcnt vmcnt(" #n ")" ::: "memory")

// One k-half (64 k-bytes): 4 B-frags at SEG, then per-m JIT A-read + 4 MFMAs.
#define HALFK(SEG)                                                              \
    {                                                                           \
        i32x4 b0 = *(const i32x4*)(Bb + rbB + 0 * 2048 + (SEG));                \
        i32x4 b1 = *(const i32x4*)(Bb + rbB + 1 * 2048 + (SEG));                \
        i32x4 b2 = *(const i32x4*)(Bb + rbB + 2 * 2048 + (SEG));                \
        i32x4 b3 = *(const i32x4*)(Bb + rbB + 3 * 2048 + (SEG));                \
        _Pragma("unroll")                                                       \
        for (int m = 0; m < 4; ++m) {                                           \
            i32x4 a = *(const i32x4*)(Ab + rbA + m * 2048 + (SEG));             \
            __builtin_amdgcn_s_setprio(1);                                      \
            acc[m][0] = __builtin_amdgcn_mfma_i32_16x16x64_i8(a, b0, acc[m][0], 0, 0, 0); \
            acc[m][1] = __builtin_amdgcn_mfma_i32_16x16x64_i8(a, b1, acc[m][1], 0, 0, 0); \
            acc[m][2] = __builtin_amdgcn_mfma_i32_16x16x64_i8(a, b2, acc[m][2], 0, 0, 0); \
            acc[m][3] = __builtin_amdgcn_mfma_i32_16x16x64_i8(a, b3, acc[m][3], 0, 0, 0); \
            __builtin_amdgcn_s_setprio(0);                                      \
        }                                                                       \
    }

__global__ __launch_bounds__(1024) void gemm_kernel(const signed char* __restrict__ n1,
                                                    const signed char* __restrict__ n2,
                                                    const float* __restrict__ inva,
                                                    const float* __restrict__ invb,
                                                    float* __restrict__ partial) {
    extern __shared__ char smem[];
    int t = threadIdx.x;
    int l = t & 63;
    int w = t >> 6;    // 0..15
    int wr = w >> 2;   // 0..3 -> A 64-row band
    int wc = w & 3;    // 0..3 -> B 64-col band

    // XCD-aware + L2 supertile mapping (1024 blocks, bijective)
    int bid = blockIdx.x;
    int xcd = bid & 7, idx = bid >> 3;
    int br = xcd * 4 + (idx & 3);
    int bc = (idx >> 4) * 4 + ((idx >> 2) & 3);
    int rowbase = br * BM, colbase = bc * BN;

    // staging: thread t covers LDS row sr = t>>3 (+128j), granule t&7;
    // inverse-swizzled global 16B-granule = (t&7) ^ (sr&7)
    int sr = t >> 3;
    int gcol0 = ((t & 7) ^ (sr & 7)) * 16;
    const signed char* Ag = n1 + (size_t)(rowbase + sr) * DIM + gcol0;
    const signed char* Bg = n2 + (size_t)(colbase + sr) * DIM + gcol0;

    i32x4 acc[4][4] = {};   // 64 regs (AGPR)

    // read side: frag row r = l&15 (bands multiples of 64 -> r&7 = l&7),
    // true granule = (l>>4) + 4*ks, slot = granule ^ (l&7)
    int seg0 = (((l >> 4) + 0) ^ (l & 7)) * 16;
    int seg1 = (((l >> 4) + 4) ^ (l & 7)) * 16;
    // cselect wave-stagger: odd waves do the seg1 half first (runtime values, no code dup)
    int stag = w & 1;
    int segA = stag ? seg1 : seg0;
    int segB = stag ? seg0 : seg1;
    int rbA = (wr * 64 + (l & 15)) * 128;
    int rbB = (wc * 64 + (l & 15)) * 128;

    // prologue: stage K-tile 0 into parity 0
    stG(Ag, smem, t, 0);         stG(Ag, smem, t, 1);
    stG(Bg, smem + 65536, t, 0); stG(Bg, smem + 65536, t, 1);
    VMW(0); BAR();

    #pragma unroll
    for (int kt = 0; kt < KTILES - 1; ++kt) {
        int db = kt & 1;
        const char* Ab = smem + db * 32768;
        const char* Bb = smem + 65536 + db * 32768;
        char* AnW = smem + (db ^ 1) * 32768;
        char* BnW = smem + 65536 + (db ^ 1) * 32768;
        const signed char* Agn = Ag + (kt + 1) * BKB;
        const signed char* Bgn = Bg + (kt + 1) * BKB;

        // stage next tile, then compute both k-halves (order per-wave staggered)
        stG(Agn, AnW, t, 0); stG(Agn, AnW, t, 1);
        stG(Bgn, BnW, t, 0); stG(Bgn, BnW, t, 1);
        HALFK(segA);
        HALFK(segB);
        VMW(0); BAR();
    }
    {   // peeled last tile (kt = 5, parity 1): no staging
        const char* Ab = smem + 32768;
        const char* Bb = smem + 65536 + 32768;
        HALFK(segA);
        HALFK(segB);
    }

    // ---------------- epilogue: cos = acc * inva[row] * invb[col]; t-Student + row sums ----------------
    // C/D map: row = wr*64 + m*16 + (l>>4)*4 + j (A-side), col = wc*64 + n*16 + (l&15)
    float invb_n[4];
    #pragma unroll
    for (int n = 0; n < 4; ++n)
        invb_n[n] = invb[colbase + wc * 64 + n * 16 + (l & 15)];

    float* red = (float*)smem;  // 256 rows x 4 wc
    __syncthreads();
    #pragma unroll
    for (int m = 0; m < 4; ++m) {
        f32x4 ia = *(const f32x4*)(inva + rowbase + wr * 64 + m * 16 + (l >> 4) * 4);
        #pragma unroll
        for (int j = 0; j < 4; ++j) {
            float s = 0.f;
            #pragma unroll
            for (int n = 0; n < 4; ++n) {
                float cos = (float)acc[m][n][j] * ia[j] * invb_n[n];
                s += tstudent(cos);
            }
            s += __shfl_xor(s, 1);
            s += __shfl_xor(s, 2);
            s += __shfl_xor(s, 4);
            s += __shfl_xor(s, 8);
            if ((l & 15) == 0) {
                int row = wr * 64 + m * 16 + (l >> 4) * 4 + j;
                red[row * 4 + wc] = s;
            }
        }
    }
    __syncthreads();
    if (t < BM) {
        partial[(size_t)bc * N_ROWS + rowbase + t] = red[t * 4 + 0] + red[t * 4 + 1] + red[t * 4 + 2] + red[t * 4 + 3];
    }
}

// ---------------- kernel 3: per-row denom + ratio, per-block sums ----------------
__global__ __launch_bounds__(256) void reduce_kernel(const float* __restrict__ partial,
                                                     const float* __restrict__ num,
                                                     float* __restrict__ blocksum) {
    int row = blockIdx.x * 256 + threadIdx.x;
    float d = 0.f;
    #pragma unroll 8
    for (int ct = 0; ct < NT2; ++ct) d += partial[(size_t)ct * N_ROWS + row];
    float s = num[row] / d;
    for (int off = 32; off; off >>= 1) s += __shfl_down(s, off);
    __shared__ float wsum[4];
    if ((threadIdx.x & 63) == 0) wsum[threadIdx.x >> 6] = s;
    __syncthreads();
    if (threadIdx.x == 0) blocksum[blockIdx.x] = wsum[0] + wsum[1] + wsum[2] + wsum[3];
}

// ---------------- kernel 4: final scalar ----------------
__global__ __launch_bounds__(64) void final_kernel(const float* __restrict__ blocksum,
                                                   float* __restrict__ out) {
    int l = threadIdx.x;
    float s = (l < 32) ? blocksum[l] : 0.f;
    for (int off = 32; off; off >>= 1) s += __shfl_down(s, off);
    if (l == 0) out[0] = -(s / (float)N_ROWS);
}

extern "C" void kernel_launch(void* const* d_in, const int* in_sizes, int n_in,
                              void* d_out, int out_size, void* d_ws, size_t ws_size,
                              hipStream_t stream) {
    const float* z1 = (const float*)d_in[0];
    const float* z2 = (const float*)d_in[1];
    char* ws = (char*)d_ws;
    const size_t n_bytes = (size_t)N_ROWS * DIM;   // 6,291,456 (int8)
    signed char* n1 = (signed char*)ws;
    signed char* n2 = (signed char*)(ws + n_bytes);
    size_t base2 = 2 * n_bytes;
    float* num      = (float*)(ws + base2);                    // 32 KB
    float* inva     = (float*)(ws + base2 + 32768);            // 32 KB
    float* invb     = (float*)(ws + base2 + 65536);            // 32 KB
    float* partial  = (float*)(ws + base2 + 98304);            // 1 MB used
    float* blocksum = (float*)(ws + base2 + 98304 + 2097152);  // 128 B

    hipFuncSetAttribute((const void*)gemm_kernel,
                        hipFuncAttributeMaxDynamicSharedMemorySize, LDS_BYTES);

    norm_kernel<<<N_ROWS, 256, 0, stream>>>(z1, z2, n1, n2, num, inva, invb);
    gemm_kernel<<<NT2 * NT2, 1024, LDS_BYTES, stream>>>(n1, n2, inva, invb, partial);
    reduce_kernel<<<N_ROWS / 256, 256, 0, stream>>>(partial, num, blocksum);
    final_kernel<<<1, 64, 0, stream>>>(blocksum, (float*)d_out);
}